// Round 4
// baseline (223.760 us; speedup 1.0000x reference)
//
#include <hip/hip_runtime.h>

#define HID    128     // hidden width per half
#define K256   256
#define TILE_M 64
#define TILE_E 64

typedef __attribute__((ext_vector_type(8))) short bf16x8;
typedef __attribute__((ext_vector_type(4))) float floatx4;

__device__ __forceinline__ unsigned short f2bf(float f) {
  union { float f; unsigned u; } v; v.f = f;
  return (unsigned short)((v.u + 0x7FFFu + ((v.u >> 16) & 1u)) >> 16);  // RNE
}
__device__ __forceinline__ float bf2f(short s) {
  union { unsigned u; float f; } v; v.u = ((unsigned)(unsigned short)s) << 16;
  return v.f;
}
__device__ __forceinline__ bf16x8 pack8(float4 a, float4 b) {
  bf16x8 r;
  r[0] = (short)f2bf(a.x); r[1] = (short)f2bf(a.y);
  r[2] = (short)f2bf(a.z); r[3] = (short)f2bf(a.w);
  r[4] = (short)f2bf(b.x); r[5] = (short)f2bf(b.y);
  r[6] = (short)f2bf(b.z); r[7] = (short)f2bf(b.w);
  return r;
}

// ---------------- Phase 1: H = z * W1halfT  (M x 128, K=128) ----------------
__global__ __launch_bounds__(256, 4)
void node_proj(const float* __restrict__ zs, const float* __restrict__ zd,
               const float* __restrict__ W1,
               unsigned short* __restrict__ Hs, unsigned short* __restrict__ Hd,
               int M)
{
  __shared__ unsigned short At[TILE_M * HID];  // 16 KiB

  const int which = blockIdx.y;
  const float* __restrict__ z = which ? zd : zs;
  unsigned short* __restrict__ H = which ? Hd : Hs;
  const int koff = which * HID;

  const int tid  = threadIdx.x;
  const int lane = tid & 63;
  const int w    = tid >> 6;
  const int nlo  = lane & 15;
  const int quad = lane >> 4;
  const int r0   = blockIdx.x * TILE_M;

#pragma unroll
  for (int i = 0; i < 4; ++i) {
    const int c   = tid + i * 256;
    const int row = c >> 4;
    const int c16 = c & 15;
    const int gr  = r0 + row;
    bf16x8 v = (bf16x8){0,0,0,0,0,0,0,0};
    if (gr < M) {
      const float* p = z + (size_t)gr * HID + c16 * 8;
      v = pack8(*(const float4*)p, *(const float4*)(p + 4));
    }
    *(bf16x8*)(At + row * HID + ((c16 ^ (row & 15)) * 8)) = v;
  }

  bf16x8 bfr[2][4];
  const int nb = w * 32;
#pragma unroll
  for (int nt = 0; nt < 2; ++nt) {
    const int n = nb + nt * 16 + nlo;
#pragma unroll
    for (int kt = 0; kt < 4; ++kt) {
      const float* p = W1 + (size_t)n * K256 + koff + kt * 32 + quad * 8;
      bfr[nt][kt] = pack8(*(const float4*)p, *(const float4*)(p + 4));
    }
  }
  __syncthreads();

  floatx4 acc[4][2];
#pragma unroll
  for (int mt = 0; mt < 4; ++mt)
#pragma unroll
    for (int nt = 0; nt < 2; ++nt)
      acc[mt][nt] = (floatx4){0.f, 0.f, 0.f, 0.f};

#pragma unroll
  for (int kt = 0; kt < 4; ++kt) {
    bf16x8 a[4];
#pragma unroll
    for (int mt = 0; mt < 4; ++mt) {
      const int m  = mt * 16 + nlo;
      const int cs = (kt * 4 + quad) ^ nlo;
      a[mt] = *(const bf16x8*)(At + m * HID + cs * 8);
    }
#pragma unroll
    for (int mt = 0; mt < 4; ++mt)
#pragma unroll
      for (int nt = 0; nt < 2; ++nt)
        acc[mt][nt] = __builtin_amdgcn_mfma_f32_16x16x32_bf16(
            a[mt], bfr[nt][kt], acc[mt][nt], 0, 0, 0);
  }

#pragma unroll
  for (int mt = 0; mt < 4; ++mt) {
#pragma unroll
    for (int r = 0; r < 4; ++r) {
      const int row = r0 + mt * 16 + quad * 4 + r;
      if (row < M) {
#pragma unroll
        for (int nt = 0; nt < 2; ++nt)
          H[(size_t)row * HID + nb + nt * 16 + nlo] = f2bf(acc[mt][nt][r]);
      }
    }
  }
}

// ---------------- Phase 2: out[e] = W2 . relu(Hs[row]+Hd[col]+b1) + b2 ----------------
// One 64-edge batch per block (no loop): MLP from block turnover, not loop iterations.
// 16 lanes per edge-group, 4 edges per group, zero LDS, launch_bounds(256,8) -> 32 waves/CU.
__global__ __launch_bounds__(256, 8)
void edge_eval(const unsigned short* __restrict__ Hs,
               const unsigned short* __restrict__ Hd,
               const int* __restrict__ eidx,
               const float* __restrict__ b1, const float* __restrict__ W2,
               const float* __restrict__ b2,
               float* __restrict__ out, int E)
{
  const int tid = threadIdx.x;
  const int l16 = tid & 15;
  const int ebase = blockIdx.x * 64 + (tid >> 4) * 4;

  int rows[4], cols[4];
#pragma unroll
  for (int u = 0; u < 4; ++u) {
    const int e = ebase + u;
    const bool ok = e < E;
    rows[u] = ok ? eidx[e] : 0;
    cols[u] = ok ? eidx[E + e] : 0;
  }

  bf16x8 hs[4], hd[4];
#pragma unroll
  for (int u = 0; u < 4; ++u)
    hs[u] = *(const bf16x8*)(Hs + (size_t)rows[u] * HID + l16 * 8);
#pragma unroll
  for (int u = 0; u < 4; ++u)
    hd[u] = *(const bf16x8*)(Hd + (size_t)cols[u] * HID + l16 * 8);

  float4 b1a = *(const float4*)(b1 + l16 * 8);
  float4 b1b = *(const float4*)(b1 + l16 * 8 + 4);
  float4 w2a = *(const float4*)(W2 + l16 * 8);
  float4 w2b = *(const float4*)(W2 + l16 * 8 + 4);
  const float b1v[8] = {b1a.x, b1a.y, b1a.z, b1a.w, b1b.x, b1b.y, b1b.z, b1b.w};
  const float w2v[8] = {w2a.x, w2a.y, w2a.z, w2a.w, w2b.x, w2b.y, w2b.z, w2b.w};
  const float bias2 = b2[0];

  float v[4];
#pragma unroll
  for (int u = 0; u < 4; ++u) {
    float s = 0.f;
#pragma unroll
    for (int j = 0; j < 8; ++j) {
      float x = bf2f(hs[u][j]) + bf2f(hd[u][j]) + b1v[j];
      x = fmaxf(x, 0.f);
      s = fmaf(x, w2v[j], s);
    }
    s += __shfl_xor(s, 1);
    s += __shfl_xor(s, 2);
    s += __shfl_xor(s, 4);
    s += __shfl_xor(s, 8);
    v[u] = s;
  }
  if (l16 < 4) {
    const int e = ebase + l16;
    const float vo = (l16 == 0) ? v[0] : (l16 == 1) ? v[1] : (l16 == 2) ? v[2] : v[3];
    if (e < E) out[e] = vo + bias2;
  }
}

// ---------------- Fallback (ws too small): fused kernel, fp32 direct ----------------
__global__ __launch_bounds__(256, 4)
void edge_decoder_f32(const float* __restrict__ zsrc_f, const float* __restrict__ zdst_f,
                      const int* __restrict__ eidx,
                      const float* __restrict__ W1f,
                      const float* __restrict__ b1, const float* __restrict__ W2,
                      const float* __restrict__ b2,
                      float* __restrict__ out, int E)
{
  __shared__ unsigned short Zt[TILE_E * K256];
  __shared__ int   idxs[2 * TILE_E];
  __shared__ float part[4 * TILE_E];

  const int tid  = threadIdx.x;
  const int lane = tid & 63;
  const int nh   = tid >> 6;
  const int nlo  = lane & 15;
  const int quad = lane >> 4;
  const int e0   = blockIdx.x * TILE_E;

  if (tid < 2 * TILE_E) {
    const int ee = e0 + (tid & 63);
    idxs[tid] = (ee < E) ? eidx[(tid >> 6) * E + ee] : 0;
  }
  __syncthreads();

#pragma unroll
  for (int it = 0; it < 8; ++it) {
    const int c   = tid + it * 256;
    const int row = c >> 4;
    const int l16 = c & 15;
    const int e   = row >> 1;
    const int h   = row & 1;
    const int node = idxs[h * TILE_E + e];
    const int cs  = ((h << 4) | l16) ^ (e & 31);
    const float* p = (h ? zdst_f : zsrc_f) + (size_t)node * HID + l16 * 8;
    bf16x8 v = pack8(*(const float4*)p, *(const float4*)(p + 4));
    *(bf16x8*)(Zt + e * K256 + cs * 8) = v;
  }
  __syncthreads();

  bf16x8 w1f[2][8];
  const int nb = nh * 32;
#pragma unroll
  for (int nt = 0; nt < 2; ++nt) {
    const int n = nb + nt * 16 + nlo;
#pragma unroll
    for (int kt = 0; kt < 8; ++kt) {
      const float* p = W1f + (size_t)n * K256 + kt * 32 + quad * 8;
      w1f[nt][kt] = pack8(*(const float4*)p, *(const float4*)(p + 4));
    }
  }

  floatx4 acc[4][2];
#pragma unroll
  for (int mt = 0; mt < 4; ++mt)
#pragma unroll
    for (int nt = 0; nt < 2; ++nt)
      acc[mt][nt] = (floatx4){0.f, 0.f, 0.f, 0.f};

#pragma unroll
  for (int kt = 0; kt < 8; ++kt) {
    bf16x8 a[4];
#pragma unroll
    for (int mt = 0; mt < 4; ++mt) {
      const int m  = mt * 16 + nlo;
      const int cs = (kt * 4 + quad) ^ (m & 31);
      a[mt] = *(const bf16x8*)(Zt + m * K256 + cs * 8);
    }
#pragma unroll
    for (int mt = 0; mt < 4; ++mt)
#pragma unroll
      for (int nt = 0; nt < 2; ++nt)
        acc[mt][nt] = __builtin_amdgcn_mfma_f32_16x16x32_bf16(
            a[mt], w1f[nt][kt], acc[mt][nt], 0, 0, 0);
  }

  float b1v[2], w2v[2];
#pragma unroll
  for (int nt = 0; nt < 2; ++nt) {
    const int n = nb + nt * 16 + nlo;
    b1v[nt] = b1[n];
    w2v[nt] = W2[n];
  }
#pragma unroll
  for (int mt = 0; mt < 4; ++mt) {
#pragma unroll
    for (int r = 0; r < 4; ++r) {
      float v = 0.f;
#pragma unroll
      for (int nt = 0; nt < 2; ++nt) {
        float x = acc[mt][nt][r] + b1v[nt];
        x = fmaxf(x, 0.f);
        v = fmaf(x, w2v[nt], v);
      }
      v += __shfl_xor(v, 1);
      v += __shfl_xor(v, 2);
      v += __shfl_xor(v, 4);
      v += __shfl_xor(v, 8);
      if (nlo == 0)
        part[nh * TILE_E + mt * 16 + quad * 4 + r] = v;
    }
  }
  __syncthreads();
  if (tid < TILE_E && e0 + tid < E)
    out[e0 + tid] = part[tid] + part[TILE_E + tid] + part[2 * TILE_E + tid]
                  + part[3 * TILE_E + tid] + b2[0];
}

extern "C" void kernel_launch(void* const* d_in, const int* in_sizes, int n_in,
                              void* d_out, int out_size, void* d_ws, size_t ws_size,
                              hipStream_t stream) {
  const float* z_src = (const float*)d_in[0];
  const float* z_dst = (const float*)d_in[1];
  const int*   eidx  = (const int*)d_in[2];
  const float* W1    = (const float*)d_in[3];
  const float* b1    = (const float*)d_in[4];
  const float* W2    = (const float*)d_in[5];
  const float* b2    = (const float*)d_in[6];
  float* out = (float*)d_out;

  const int NH = in_sizes[0];        // 12,800,000 = M * 128
  const int M  = NH / HID;           // 100,000
  const int E  = in_sizes[2] / 2;    // 1,000,000

  const size_t need = (size_t)M * HID * 2 * sizeof(unsigned short);  // Hs + Hd
  if (ws_size >= need) {
    unsigned short* Hs = (unsigned short*)d_ws;
    unsigned short* Hd = Hs + (size_t)M * HID;
    const int nMt = (M + TILE_M - 1) / TILE_M;   // 1563
    node_proj<<<dim3(nMt, 2), 256, 0, stream>>>(z_src, z_dst, W1, Hs, Hd, M);
    edge_eval<<<(E + 63) / 64, 256, 0, stream>>>(Hs, Hd, eidx, b1, W2, b2, out, E);
  } else {
    const int nblk = (E + TILE_E - 1) / TILE_E;
    edge_decoder_f32<<<nblk, 256, 0, stream>>>(z_src, z_dst, eidx, W1, b1, W2, b2, out, E);
  }
}

// Round 5
// 221.144 us; speedup vs baseline: 1.0118x; 1.0118x over previous
//
#include <hip/hip_runtime.h>

#define HID    128     // hidden width per half
#define K256   256
#define TILE_M 64      // rows per subtile
#define SUB    4       // subtiles per block -> 256 rows/block
#define TILE_E 64

typedef __attribute__((ext_vector_type(8))) short bf16x8;
typedef __attribute__((ext_vector_type(4))) float floatx4;

__device__ __forceinline__ unsigned short f2bf(float f) {
  union { float f; unsigned u; } v; v.f = f;
  return (unsigned short)((v.u + 0x7FFFu + ((v.u >> 16) & 1u)) >> 16);  // RNE
}
__device__ __forceinline__ float bf2f(short s) {
  union { unsigned u; float f; } v; v.u = ((unsigned)(unsigned short)s) << 16;
  return v.f;
}
__device__ __forceinline__ bf16x8 pack8(float4 a, float4 b) {
  bf16x8 r;
  r[0] = (short)f2bf(a.x); r[1] = (short)f2bf(a.y);
  r[2] = (short)f2bf(a.z); r[3] = (short)f2bf(a.w);
  r[4] = (short)f2bf(b.x); r[5] = (short)f2bf(b.y);
  r[6] = (short)f2bf(b.z); r[7] = (short)f2bf(b.w);
  return r;
}

// ---------------- Phase 1: H = z * W1halfT  (M x 128, K=128) ----------------
// 256 rows/block (4 serial 64-row subtiles; W1 frags amortized). Epilogue
// transposes C through LDS (XOR-swizzled) so H stores are coalesced bf16x8.
__global__ __launch_bounds__(256, 4)
void node_proj(const float* __restrict__ zs, const float* __restrict__ zd,
               const float* __restrict__ W1,
               unsigned short* __restrict__ Hs, unsigned short* __restrict__ Hd,
               int M)
{
  __shared__ unsigned short At[TILE_M * HID];  // 16 KiB, reused: A-tile then C-tile

  const int which = blockIdx.y;
  const float* __restrict__ z = which ? zd : zs;
  unsigned short* __restrict__ H = which ? Hd : Hs;
  const int koff = which * HID;

  const int tid  = threadIdx.x;
  const int lane = tid & 63;
  const int w    = tid >> 6;
  const int nlo  = lane & 15;
  const int quad = lane >> 4;

  // W1 B-fragments once per block (this wave's 32 out-cols)
  bf16x8 bfr[2][4];
  const int nb = w * 32;
#pragma unroll
  for (int nt = 0; nt < 2; ++nt) {
    const int n = nb + nt * 16 + nlo;
#pragma unroll
    for (int kt = 0; kt < 4; ++kt) {
      const float* p = W1 + (size_t)n * K256 + koff + kt * 32 + quad * 8;
      bfr[nt][kt] = pack8(*(const float4*)p, *(const float4*)(p + 4));
    }
  }

  const int rbase = blockIdx.x * (TILE_M * SUB);

  for (int s = 0; s < SUB; ++s) {
    const int r0 = rbase + s * TILE_M;
    if (r0 >= M) break;                      // uniform across block

    __syncthreads();                          // prior subtile's At reads done
    // ---- stage A-tile (fp32 -> bf16), 1024 16B chunks, XOR swizzle ----
#pragma unroll
    for (int i = 0; i < 4; ++i) {
      const int c   = tid + i * 256;
      const int row = c >> 4;
      const int c16 = c & 15;
      const int gr  = r0 + row;
      bf16x8 v = (bf16x8){0,0,0,0,0,0,0,0};
      if (gr < M) {
        const float* p = z + (size_t)gr * HID + c16 * 8;
        v = pack8(*(const float4*)p, *(const float4*)(p + 4));
      }
      *(bf16x8*)(At + row * HID + ((c16 ^ (row & 15)) * 8)) = v;
    }
    __syncthreads();

    // ---- MFMA ----
    floatx4 acc[4][2];
#pragma unroll
    for (int mt = 0; mt < 4; ++mt)
#pragma unroll
      for (int nt = 0; nt < 2; ++nt)
        acc[mt][nt] = (floatx4){0.f, 0.f, 0.f, 0.f};

#pragma unroll
    for (int kt = 0; kt < 4; ++kt) {
      bf16x8 a[4];
#pragma unroll
      for (int mt = 0; mt < 4; ++mt) {
        const int m  = mt * 16 + nlo;
        const int cs = (kt * 4 + quad) ^ nlo;
        a[mt] = *(const bf16x8*)(At + m * HID + cs * 8);
      }
#pragma unroll
      for (int mt = 0; mt < 4; ++mt)
#pragma unroll
        for (int nt = 0; nt < 2; ++nt)
          acc[mt][nt] = __builtin_amdgcn_mfma_f32_16x16x32_bf16(
              a[mt], bfr[nt][kt], acc[mt][nt], 0, 0, 0);
    }

    __syncthreads();                          // all A reads done -> reuse At for C
    // ---- C -> LDS (bf16, same XOR-chunk swizzle) ----
#pragma unroll
    for (int mt = 0; mt < 4; ++mt) {
#pragma unroll
      for (int r = 0; r < 4; ++r) {
        const int rowl = mt * 16 + quad * 4 + r;
#pragma unroll
        for (int nt = 0; nt < 2; ++nt) {
          const int col = nb + nt * 16 + nlo;
          const int sw  = ((col >> 3) ^ (rowl & 15)) * 8 + (col & 7);
          At[rowl * HID + sw] = f2bf(acc[mt][nt][r]);
        }
      }
    }
    __syncthreads();

    // ---- coalesced H store: 4 x bf16x8 per thread ----
#pragma unroll
    for (int i = 0; i < 4; ++i) {
      const int c   = tid + i * 256;
      const int row = c >> 4;
      const int c16 = c & 15;
      const int gr  = r0 + row;
      if (gr < M) {
        bf16x8 v = *(const bf16x8*)(At + row * HID + ((c16 ^ (row & 15)) * 8));
        *(bf16x8*)(H + (size_t)gr * HID + c16 * 8) = v;
      }
    }
  }
}

// ---------------- Phase 2: out[e] = W2 . relu(Hs[row]+Hd[col]+b1) + b2 ----------------
// UNCHANGED from R4 (measured at the 3.6 TB/s gather-service plateau).
__global__ __launch_bounds__(256, 8)
void edge_eval(const unsigned short* __restrict__ Hs,
               const unsigned short* __restrict__ Hd,
               const int* __restrict__ eidx,
               const float* __restrict__ b1, const float* __restrict__ W2,
               const float* __restrict__ b2,
               float* __restrict__ out, int E)
{
  const int tid = threadIdx.x;
  const int l16 = tid & 15;
  const int ebase = blockIdx.x * 64 + (tid >> 4) * 4;

  int rows[4], cols[4];
#pragma unroll
  for (int u = 0; u < 4; ++u) {
    const int e = ebase + u;
    const bool ok = e < E;
    rows[u] = ok ? eidx[e] : 0;
    cols[u] = ok ? eidx[E + e] : 0;
  }

  bf16x8 hs[4], hd[4];
#pragma unroll
  for (int u = 0; u < 4; ++u)
    hs[u] = *(const bf16x8*)(Hs + (size_t)rows[u] * HID + l16 * 8);
#pragma unroll
  for (int u = 0; u < 4; ++u)
    hd[u] = *(const bf16x8*)(Hd + (size_t)cols[u] * HID + l16 * 8);

  float4 b1a = *(const float4*)(b1 + l16 * 8);
  float4 b1b = *(const float4*)(b1 + l16 * 8 + 4);
  float4 w2a = *(const float4*)(W2 + l16 * 8);
  float4 w2b = *(const float4*)(W2 + l16 * 8 + 4);
  const float b1v[8] = {b1a.x, b1a.y, b1a.z, b1a.w, b1b.x, b1b.y, b1b.z, b1b.w};
  const float w2v[8] = {w2a.x, w2a.y, w2a.z, w2a.w, w2b.x, w2b.y, w2b.z, w2b.w};
  const float bias2 = b2[0];

  float v[4];
#pragma unroll
  for (int u = 0; u < 4; ++u) {
    float s = 0.f;
#pragma unroll
    for (int j = 0; j < 8; ++j) {
      float x = bf2f(hs[u][j]) + bf2f(hd[u][j]) + b1v[j];
      x = fmaxf(x, 0.f);
      s = fmaf(x, w2v[j], s);
    }
    s += __shfl_xor(s, 1);
    s += __shfl_xor(s, 2);
    s += __shfl_xor(s, 4);
    s += __shfl_xor(s, 8);
    v[u] = s;
  }
  if (l16 < 4) {
    const int e = ebase + l16;
    const float vo = (l16 == 0) ? v[0] : (l16 == 1) ? v[1] : (l16 == 2) ? v[2] : v[3];
    if (e < E) out[e] = vo + bias2;
  }
}

// ---------------- Fallback (ws too small): fused kernel, fp32 direct ----------------
__global__ __launch_bounds__(256, 4)
void edge_decoder_f32(const float* __restrict__ zsrc_f, const float* __restrict__ zdst_f,
                      const int* __restrict__ eidx,
                      const float* __restrict__ W1f,
                      const float* __restrict__ b1, const float* __restrict__ W2,
                      const float* __restrict__ b2,
                      float* __restrict__ out, int E)
{
  __shared__ unsigned short Zt[TILE_E * K256];
  __shared__ int   idxs[2 * TILE_E];
  __shared__ float part[4 * TILE_E];

  const int tid  = threadIdx.x;
  const int lane = tid & 63;
  const int nh   = tid >> 6;
  const int nlo  = lane & 15;
  const int quad = lane >> 4;
  const int e0   = blockIdx.x * TILE_E;

  if (tid < 2 * TILE_E) {
    const int ee = e0 + (tid & 63);
    idxs[tid] = (ee < E) ? eidx[(tid >> 6) * E + ee] : 0;
  }
  __syncthreads();

#pragma unroll
  for (int it = 0; it < 8; ++it) {
    const int c   = tid + it * 256;
    const int row = c >> 4;
    const int l16 = c & 15;
    const int e   = row >> 1;
    const int h   = row & 1;
    const int node = idxs[h * TILE_E + e];
    const int cs  = ((h << 4) | l16) ^ (e & 31);
    const float* p = (h ? zdst_f : zsrc_f) + (size_t)node * HID + l16 * 8;
    bf16x8 v = pack8(*(const float4*)p, *(const float4*)(p + 4));
    *(bf16x8*)(Zt + e * K256 + cs * 8) = v;
  }
  __syncthreads();

  bf16x8 w1f[2][8];
  const int nb = nh * 32;
#pragma unroll
  for (int nt = 0; nt < 2; ++nt) {
    const int n = nb + nt * 16 + nlo;
#pragma unroll
    for (int kt = 0; kt < 8; ++kt) {
      const float* p = W1f + (size_t)n * K256 + kt * 32 + quad * 8;
      w1f[nt][kt] = pack8(*(const float4*)p, *(const float4*)(p + 4));
    }
  }

  floatx4 acc[4][2];
#pragma unroll
  for (int mt = 0; mt < 4; ++mt)
#pragma unroll
    for (int nt = 0; nt < 2; ++nt)
      acc[mt][nt] = (floatx4){0.f, 0.f, 0.f, 0.f};

#pragma unroll
  for (int kt = 0; kt < 8; ++kt) {
    bf16x8 a[4];
#pragma unroll
    for (int mt = 0; mt < 4; ++mt) {
      const int m  = mt * 16 + nlo;
      const int cs = (kt * 4 + quad) ^ (m & 31);
      a[mt] = *(const bf16x8*)(Zt + m * K256 + cs * 8);
    }
#pragma unroll
    for (int mt = 0; mt < 4; ++mt)
#pragma unroll
      for (int nt = 0; nt < 2; ++nt)
        acc[mt][nt] = __builtin_amdgcn_mfma_f32_16x16x32_bf16(
            a[mt], w1f[nt][kt], acc[mt][nt], 0, 0, 0);
  }

  float b1v[2], w2v[2];
#pragma unroll
  for (int nt = 0; nt < 2; ++nt) {
    const int n = nb + nt * 16 + nlo;
    b1v[nt] = b1[n];
    w2v[nt] = W2[n];
  }
#pragma unroll
  for (int mt = 0; mt < 4; ++mt) {
#pragma unroll
    for (int r = 0; r < 4; ++r) {
      float v = 0.f;
#pragma unroll
      for (int nt = 0; nt < 2; ++nt) {
        float x = acc[mt][nt][r] + b1v[nt];
        x = fmaxf(x, 0.f);
        v = fmaf(x, w2v[nt], v);
      }
      v += __shfl_xor(v, 1);
      v += __shfl_xor(v, 2);
      v += __shfl_xor(v, 4);
      v += __shfl_xor(v, 8);
      if (nlo == 0)
        part[nh * TILE_E + mt * 16 + quad * 4 + r] = v;
    }
  }
  __syncthreads();
  if (tid < TILE_E && e0 + tid < E)
    out[e0 + tid] = part[tid] + part[TILE_E + tid] + part[2 * TILE_E + tid]
                  + part[3 * TILE_E + tid] + b2[0];
}

extern "C" void kernel_launch(void* const* d_in, const int* in_sizes, int n_in,
                              void* d_out, int out_size, void* d_ws, size_t ws_size,
                              hipStream_t stream) {
  const float* z_src = (const float*)d_in[0];
  const float* z_dst = (const float*)d_in[1];
  const int*   eidx  = (const int*)d_in[2];
  const float* W1    = (const float*)d_in[3];
  const float* b1    = (const float*)d_in[4];
  const float* W2    = (const float*)d_in[5];
  const float* b2    = (const float*)d_in[6];
  float* out = (float*)d_out;

  const int NH = in_sizes[0];        // 12,800,000 = M * 128
  const int M  = NH / HID;           // 100,000
  const int E  = in_sizes[2] / 2;    // 1,000,000

  const size_t need = (size_t)M * HID * 2 * sizeof(unsigned short);  // Hs + Hd
  if (ws_size >= need) {
    unsigned short* Hs = (unsigned short*)d_ws;
    unsigned short* Hd = Hs + (size_t)M * HID;
    const int nMt = (M + TILE_M * SUB - 1) / (TILE_M * SUB);   // 391
    node_proj<<<dim3(nMt, 2), 256, 0, stream>>>(z_src, z_dst, W1, Hs, Hd, M);
    edge_eval<<<(E + 63) / 64, 256, 0, stream>>>(Hs, Hd, eidx, b1, W2, b2, out, E);
  } else {
    const int nblk = (E + TILE_E - 1) / TILE_E;
    edge_decoder_f32<<<nblk, 256, 0, stream>>>(z_src, z_dst, eidx, W1, b1, W2, b2, out, E);
  }
}